// Round 2
// baseline (183.026 us; speedup 1.0000x reference)
//
#include <hip/hip_runtime.h>
#include <hip/hip_cooperative_groups.h>

namespace cg = cooperative_groups;

#define DD 256
#define KK 54
#define BB 8
#define TT 1024
#define NCOEF 15      // 3 parts x {v0, v1, a0, a1, w}
#define TS 16         // t-strip per block in main phase
#define NBT (BB * TT) // 8192

struct Params {
  const float *barX, *W, *phi_v_w, *phi_v_b, *phi_a_w, *phi_a_b, *gamma_v, *gamma_a;
  const float *WM_w, *WM_b, *dw_w, *dw_b, *pw_w, *pw_b, *ln_w, *ln_b;
  float *mfold, *Gt, *Ht, *baset, *coef, *out;
};

// Single cooperative kernel, 512 blocks x 256 threads, 2 grid syncs.
// Phase A0: blocks 0..14  -> Mfold[15][256] (wave-dots over WM_w rows, coalesced)
//           blocks 15..   -> coef[8192][15] (17 rows per block, LDS rounds)
// Phase A1: blocks 0..48  -> Gt[45][256], Ht[3][256], base[256] (wave-dots over pw_w rows)
// Phase B : all 512 blocks -> 45-term FMA + LayerNorm, strip of 16 t's each.
__global__ __launch_bounds__(256) void fused(Params P)
{
  cg::grid_group grid = cg::this_grid();
  __shared__ __align__(16) float smem[1344];   // max use: coef phase 4*64*5 = 1280
  const int gid  = blockIdx.x;
  const int tid  = threadIdx.x;
  const int wave = tid >> 6, lane = tid & 63;

  // ---------------- Phase A0 ----------------
  if (gid < NCOEF) {
    // Mfold[i][d] = sum_e WM_w[d][p*256+e] * phi_i[e]
    const int i = gid, p = i / 5, q = i - p * 5;
    float v;
    if (q == 4) v = P.gamma_v[0] * P.phi_v_b[tid] + P.gamma_a[0] * P.phi_a_b[tid];
    else { const float* phi = (q < 2) ? P.phi_v_w : P.phi_a_w; v = phi[tid * 2 + (q & 1)]; }
    smem[tid] = v;
    __syncthreads();
    const float4 ph = ((const float4*)smem)[lane];
    for (int r = 0; r < 64; ++r) {
      const int d = wave * 64 + r;
      const float4 wv = *(const float4*)(P.WM_w + (size_t)d * (3 * DD) + p * DD + lane * 4);
      float acc = wv.x * ph.x + wv.y * ph.y + wv.z * ph.z + wv.w * ph.w;
#pragma unroll
      for (int m = 32; m; m >>= 1) acc += __shfl_xor(acc, m);
      if (lane == 0) P.mfold[i * DD + d] = acc;
    }
  } else {
    // coef rows: 17 per block, processed in 5 lockstep rounds of 4 waves
    const int base = (gid - NCOEF) * 17;
    const float gv = P.gamma_v[0], ga = P.gamma_a[0];
    for (int r0 = 0; r0 < 17; r0 += 4) {
      const int j = r0 + wave;
      const int bt = base + j;
      const bool active = (j < 17) && (bt < NBT);
      float w = 0.f, v0 = 0.f, v1 = 0.f, a0 = 0.f, a1 = 0.f;
      if (active && lane < KK) {
        const int t = bt & (TT - 1);
        w = P.W[(size_t)bt * KK + lane];
        const float2* xp = (const float2*)P.barX + ((size_t)bt * KK + lane);
        const float2 x = xp[0];
        float2 xm = make_float2(0.f, 0.f), xmm = make_float2(0.f, 0.f);
        if (t >= 1) xm  = xp[-KK];
        if (t >= 2) xmm = xp[-2 * KK];
        v0 = x.x - xm.x; v1 = x.y - xm.y;
        const float vm0 = (t >= 1) ? (xm.x - xmm.x) : 0.f;
        const float vm1 = (t >= 1) ? (xm.y - xmm.y) : 0.f;
        a0 = v0 - vm0; a1 = v1 - vm1;
      }
      float wsum = w;
#pragma unroll
      for (int m = 32; m; m >>= 1) wsum += __shfl_xor(wsum, m);
      const float wn = w * (1.f / (wsum + 1e-6f));
      float* lds = smem + wave * 64 * 5;
      if (active) {
        lds[lane * 5 + 0] = wn * v0; lds[lane * 5 + 1] = wn * v1;
        lds[lane * 5 + 2] = wn * a0; lds[lane * 5 + 3] = wn * a1;
        lds[lane * 5 + 4] = wn;
      }
      __syncthreads();
      if (active && lane < NCOEF) {
        const int p = lane / 5, q = lane - p * 5;
        const int k0 = (p == 0) ? 0  : ((p == 1) ? 12 : 33);
        const int k1 = (p == 0) ? 12 : ((p == 1) ? 33 : 54);
        float acc = 0.f;
        for (int k = k0; k < k1; ++k) acc += lds[k * 5 + q];
        if (q < 2) acc *= gv; else if (q < 4) acc *= ga;
        P.coef[(size_t)bt * NCOEF + lane] = acc;
      }
      __syncthreads();
    }
  }
  grid.sync();

  // ---------------- Phase A1 ----------------
  if (gid < 49) {
    const int o = gid;
    {
      const int d = tid;
      float c;
      if (o < 45)      { const int j = o / 15, i = o - j * 15; c = P.dw_w[d * 3 + j] * P.mfold[i * DD + d]; }
      else if (o < 48) { const int j = o - 45;                 c = P.dw_w[d * 3 + j] * P.WM_b[d]; }
      else             c = P.dw_b[d];
      smem[d] = c;
    }
    __syncthreads();
    const float4 cv = ((const float4*)smem)[lane];
    for (int r = 0; r < 64; ++r) {
      const int e = wave * 64 + r;
      const float4 pv = *(const float4*)(P.pw_w + (size_t)e * DD + lane * 4);
      float acc = pv.x * cv.x + pv.y * cv.y + pv.z * cv.z + pv.w * cv.w;
#pragma unroll
      for (int m = 32; m; m >>= 1) acc += __shfl_xor(acc, m);
      if (lane == 0) {
        if (o < 45)      P.Gt[o * DD + e] = acc;
        else if (o < 48) P.Ht[(o - 45) * DD + e] = acc;
        else             P.baset[e] = acc + P.pw_b[e];
      }
    }
  }
  grid.sync();

  // ---------------- Phase B ----------------
  {
    const int b  = gid >> 6;
    const int t0 = (gid & 63) * TS;
    const int e  = tid;
    float Gr[45];
#pragma unroll
    for (int ji = 0; ji < 45; ++ji) Gr[ji] = P.Gt[ji * DD + e];
    const float H0 = P.Ht[0 * DD + e], H1 = P.Ht[1 * DD + e], H2 = P.Ht[2 * DD + e];
    const float bs = P.baset[e];
    const float lw = P.ln_w[e], lb = P.ln_b[e];

    float* cs  = smem;         // (TS+2)*NCOEF = 270 floats
    float* red = smem + 272;   // 2*4*2 = 16 floats

    for (int idx = tid; idx < (TS + 2) * NCOEF; idx += 256) {
      const int r = idx / NCOEF, i = idx - r * NCOEF;
      const int gt = t0 - 1 + r;
      float v = 0.f;
      if (gt >= 0 && gt < TT) v = P.coef[((size_t)b * TT + gt) * NCOEF + i];
      cs[idx] = v;
    }
    __syncthreads();

    for (int tl = 0; tl < TS; ++tl) {
      const int t = t0 + tl;
      float acc = bs + H1;
      if (t > 0)      acc += H0;
      if (t < TT - 1) acc += H2;
#pragma unroll
      for (int j = 0; j < 3; ++j)
#pragma unroll
        for (int i = 0; i < NCOEF; ++i)
          acc += cs[(tl + j) * NCOEF + i] * Gr[j * NCOEF + i];

      float s = acc, ss = acc * acc;
#pragma unroll
      for (int m = 32; m; m >>= 1) { s += __shfl_xor(s, m); ss += __shfl_xor(ss, m); }
      const int par = tl & 1;
      if (lane == 0) { red[(par * 4 + wave) * 2 + 0] = s; red[(par * 4 + wave) * 2 + 1] = ss; }
      __syncthreads();
      const float fs  = red[(par * 4 + 0) * 2 + 0] + red[(par * 4 + 1) * 2 + 0]
                      + red[(par * 4 + 2) * 2 + 0] + red[(par * 4 + 3) * 2 + 0];
      const float fss = red[(par * 4 + 0) * 2 + 1] + red[(par * 4 + 1) * 2 + 1]
                      + red[(par * 4 + 2) * 2 + 1] + red[(par * 4 + 3) * 2 + 1];
      const float mu  = fs * (1.f / DD);
      const float var = fss * (1.f / DD) - mu * mu;
      const float rs  = rsqrtf(var + 1e-5f);
      P.out[((size_t)b * TT + t) * DD + e] = (acc - mu) * rs * lw + lb;
    }
  }
}

extern "C" void kernel_launch(void* const* d_in, const int* in_sizes, int n_in,
                              void* d_out, int out_size, void* d_ws, size_t ws_size,
                              hipStream_t stream) {
  Params p;
  p.barX    = (const float*)d_in[0];
  p.W       = (const float*)d_in[1];
  p.phi_v_w = (const float*)d_in[2];
  p.phi_v_b = (const float*)d_in[3];
  p.phi_a_w = (const float*)d_in[4];
  p.phi_a_b = (const float*)d_in[5];
  p.gamma_v = (const float*)d_in[6];
  p.gamma_a = (const float*)d_in[7];
  p.WM_w    = (const float*)d_in[8];
  p.WM_b    = (const float*)d_in[9];
  p.dw_w    = (const float*)d_in[10];
  p.dw_b    = (const float*)d_in[11];
  p.pw_w    = (const float*)d_in[12];
  p.pw_b    = (const float*)d_in[13];
  p.ln_w    = (const float*)d_in[14];
  p.ln_b    = (const float*)d_in[15];

  float* ws = (float*)d_ws;
  p.mfold = ws;            // 15*256  = 3840
  p.Gt    = ws + 3840;     // 45*256  = 11520
  p.Ht    = ws + 15360;    // 3*256   = 768
  p.baset = ws + 16128;    // 256
  p.coef  = ws + 16384;    // 8192*15 = 122880
  p.out   = (float*)d_out;

  void* args[] = { &p };
  hipLaunchCooperativeKernel((void*)fused, dim3(512), dim3(256), args, 0, stream);
}

// Round 3
// 41.999 us; speedup vs baseline: 4.3579x; 4.3579x over previous
//
#include <hip/hip_runtime.h>

// MotionResidualBranch — collapsed-linear formulation, 3 kernels.
//
// Everything from barX to U_pw is linear in 15 per-(b,t) scalars
// (per part p: sum_k wn*V0, wn*V1, wn*A0, wn*A1, wn). Folding phi/gamma
// through WM gives Mfold[15][256]; folding depthwise-conv3 + pointwise
// gives G[3][15][256], H[3][256], base[256]. Then
//   U_pw[b,t,e] = base[e] + sum_j H[j][e]*valid(t-1+j)
//                 + sum_{j,i} coef[b,t-1+j,i] * G[j][i][e]
// followed by LayerNorm over e.

#define DD 256
#define KK 54
#define BB 8
#define TT 1024
#define NCOEF 15
#define TS 16
#define NBT (BB * TT)

// ---------- K1: blocks 0..14 -> Mfold ; blocks 15..526 -> coef ----------
__global__ __launch_bounds__(256) void k1_mfold_coef(
    const float* __restrict__ barX, const float* __restrict__ W,
    const float* __restrict__ phi_v_w, const float* __restrict__ phi_v_b,
    const float* __restrict__ phi_a_w, const float* __restrict__ phi_a_b,
    const float* __restrict__ gamma_v, const float* __restrict__ gamma_a,
    const float* __restrict__ WM_w,
    float* __restrict__ mfold, float* __restrict__ coef)
{
  const int tid = threadIdx.x;
  const int wave = tid >> 6, lane = tid & 63;
  __shared__ __align__(16) float smem[1344];

  if (blockIdx.x < NCOEF) {
    // Mfold[i][d] = sum_c WM_w[d][p*256+c] * phi_comb[c]
    const int i = blockIdx.x, p = i / 5, q = i - p * 5;
    float v;
    if (q == 4) v = gamma_v[0] * phi_v_b[tid] + gamma_a[0] * phi_a_b[tid];
    else { const float* phi = (q < 2) ? phi_v_w : phi_a_w; v = phi[tid * 2 + (q & 1)]; }
    smem[tid] = v;
    __syncthreads();
    const int d = tid;
    const float4* wrow = (const float4*)(WM_w + (size_t)d * (3 * DD) + p * DD);
    const float4* ph   = (const float4*)smem;
    float acc = 0.f;
#pragma unroll 8
    for (int c4 = 0; c4 < DD / 4; ++c4) {
      const float4 wv = wrow[c4], pv = ph[c4];
      acc += wv.x * pv.x + wv.y * pv.y + wv.z * pv.z + wv.w * pv.w;
    }
    mfold[i * DD + d] = acc;
  } else {
    // coef: 16 rows per block, 4 rounds of 4 waves
    const int base = (blockIdx.x - NCOEF) * 16;
    const float gv = gamma_v[0], ga = gamma_a[0];
    float* lds = smem + wave * 64 * 5;
    for (int r = 0; r < 4; ++r) {
      const int bt = base + r * 4 + wave;
      const int t = bt & (TT - 1);
      float w = 0.f, v0 = 0.f, v1 = 0.f, a0 = 0.f, a1 = 0.f;
      if (lane < KK) {
        w = W[(size_t)bt * KK + lane];
        const float2* xp = (const float2*)barX + ((size_t)bt * KK + lane);
        const float2 x = xp[0];
        float2 xm = make_float2(0.f, 0.f), xmm = make_float2(0.f, 0.f);
        if (t >= 1) xm  = xp[-KK];
        if (t >= 2) xmm = xp[-2 * KK];
        v0 = x.x - xm.x; v1 = x.y - xm.y;
        const float vm0 = (t >= 1) ? (xm.x - xmm.x) : 0.f;
        const float vm1 = (t >= 1) ? (xm.y - xmm.y) : 0.f;
        a0 = v0 - vm0; a1 = v1 - vm1;
      }
      float wsum = w;
#pragma unroll
      for (int m = 32; m; m >>= 1) wsum += __shfl_xor(wsum, m);
      const float wn = w * (1.f / (wsum + 1e-6f));
      lds[lane * 5 + 0] = wn * v0; lds[lane * 5 + 1] = wn * v1;
      lds[lane * 5 + 2] = wn * a0; lds[lane * 5 + 3] = wn * a1;
      lds[lane * 5 + 4] = wn;
      __syncthreads();
      if (lane < NCOEF) {
        const int p = lane / 5, q = lane - p * 5;
        const int k0 = (p == 0) ? 0  : ((p == 1) ? 12 : 33);
        const int k1 = (p == 0) ? 12 : ((p == 1) ? 33 : 54);
        float acc = 0.f;
        for (int k = k0; k < k1; ++k) acc += lds[k * 5 + q];
        if (q < 2) acc *= gv; else if (q < 4) acc *= ga;
        coef[(size_t)bt * NCOEF + lane] = acc;
      }
      __syncthreads();
    }
  }
}

// ---------- K2: 49 blocks -> Gt[45][256], Ht[3][256], base[256] ----------
__global__ __launch_bounds__(256) void k2_tables(
    const float* __restrict__ mfold, const float* __restrict__ WM_b,
    const float* __restrict__ dw_w, const float* __restrict__ dw_b,
    const float* __restrict__ pw_w, const float* __restrict__ pw_b,
    float* __restrict__ Gt, float* __restrict__ Ht, float* __restrict__ baset)
{
  const int o = blockIdx.x;          // 0..48
  const int e = threadIdx.x;
  __shared__ __align__(16) float cvec[DD];
  {
    const int d = e;
    float c;
    if (o < 45)      { const int j = o / 15, i = o - j * 15; c = dw_w[d * 3 + j] * mfold[i * DD + d]; }
    else if (o < 48) { const int j = o - 45;                 c = dw_w[d * 3 + j] * WM_b[d]; }
    else             c = dw_b[d];
    cvec[d] = c;
  }
  __syncthreads();
  const float4* prow = (const float4*)(pw_w + (size_t)e * DD);
  const float4* cv   = (const float4*)cvec;
  float acc = 0.f;
#pragma unroll 8
  for (int d4 = 0; d4 < DD / 4; ++d4) {
    const float4 pv = prow[d4], c4 = cv[d4];
    acc += pv.x * c4.x + pv.y * c4.y + pv.z * c4.z + pv.w * c4.w;
  }
  if (o < 45)      Gt[o * DD + e] = acc;
  else if (o < 48) Ht[(o - 45) * DD + e] = acc;
  else             baset[e] = acc + pw_b[e];
}

// ---------- K3: main — 45-FMA matvec + LayerNorm ----------
// __launch_bounds__(256, 1): allow the allocator full VGPR budget so
// Gr[45] stays in registers (the r2 coop kernel spilled it at 36 VGPRs).
__global__ __launch_bounds__(256, 1) void k3_main(
    const float* __restrict__ coef, const float* __restrict__ Gt,
    const float* __restrict__ Ht, const float* __restrict__ baset,
    const float* __restrict__ ln_w, const float* __restrict__ ln_b,
    float* __restrict__ out)
{
  const int b  = blockIdx.x >> 6;
  const int t0 = (blockIdx.x & 63) * TS;
  const int e  = threadIdx.x;
  const int wave = e >> 6, lane = e & 63;

  float Gr[45];
#pragma unroll
  for (int ji = 0; ji < 45; ++ji) Gr[ji] = Gt[ji * DD + e];
  const float H0 = Ht[0 * DD + e], H1 = Ht[1 * DD + e], H2 = Ht[2 * DD + e];
  const float bs = baset[e];
  const float lw = ln_w[e], lb = ln_b[e];

  __shared__ float cs[(TS + 2) * NCOEF];   // 270
  __shared__ float red[2][4][2];

  for (int idx = e; idx < (TS + 2) * NCOEF; idx += 256) {
    const int r = idx / NCOEF, i = idx - r * NCOEF;
    const int gt = t0 - 1 + r;
    float v = 0.f;
    if (gt >= 0 && gt < TT) v = coef[((size_t)b * TT + gt) * NCOEF + i];
    cs[idx] = v;
  }
  __syncthreads();

  for (int tl = 0; tl < TS; ++tl) {
    const int t = t0 + tl;
    float acc = bs + H1;
    if (t > 0)      acc += H0;
    if (t < TT - 1) acc += H2;
#pragma unroll
    for (int j = 0; j < 3; ++j)
#pragma unroll
      for (int i = 0; i < NCOEF; ++i)
        acc += cs[(tl + j) * NCOEF + i] * Gr[j * NCOEF + i];

    float s = acc, ss = acc * acc;
#pragma unroll
    for (int m = 32; m; m >>= 1) { s += __shfl_xor(s, m); ss += __shfl_xor(ss, m); }
    const int par = tl & 1;
    if (lane == 0) { red[par][wave][0] = s; red[par][wave][1] = ss; }
    __syncthreads();
    const float fs  = red[par][0][0] + red[par][1][0] + red[par][2][0] + red[par][3][0];
    const float fss = red[par][0][1] + red[par][1][1] + red[par][2][1] + red[par][3][1];
    const float mu  = fs * (1.f / DD);
    const float var = fss * (1.f / DD) - mu * mu;
    const float rs  = rsqrtf(var + 1e-5f);
    out[((size_t)b * TT + t) * DD + e] = (acc - mu) * rs * lw + lb;
  }
}

extern "C" void kernel_launch(void* const* d_in, const int* in_sizes, int n_in,
                              void* d_out, int out_size, void* d_ws, size_t ws_size,
                              hipStream_t stream) {
  const float* barX    = (const float*)d_in[0];
  const float* W       = (const float*)d_in[1];
  const float* phi_v_w = (const float*)d_in[2];
  const float* phi_v_b = (const float*)d_in[3];
  const float* phi_a_w = (const float*)d_in[4];
  const float* phi_a_b = (const float*)d_in[5];
  const float* gamma_v = (const float*)d_in[6];
  const float* gamma_a = (const float*)d_in[7];
  const float* WM_w    = (const float*)d_in[8];
  const float* WM_b    = (const float*)d_in[9];
  const float* dw_w    = (const float*)d_in[10];
  const float* dw_b    = (const float*)d_in[11];
  const float* pw_w    = (const float*)d_in[12];
  const float* pw_b    = (const float*)d_in[13];
  const float* ln_w    = (const float*)d_in[14];
  const float* ln_b    = (const float*)d_in[15];
  float* out = (float*)d_out;

  float* ws    = (float*)d_ws;
  float* mfold = ws;            // 15*256  = 3840
  float* Gt    = ws + 3840;     // 45*256  = 11520
  float* Ht    = ws + 15360;    // 3*256   = 768
  float* baset = ws + 16128;    // 256
  float* coef  = ws + 16384;    // 8192*15 = 122880

  hipLaunchKernelGGL(k1_mfold_coef, dim3(NCOEF + NBT / 16), dim3(256), 0, stream,
                     barX, W, phi_v_w, phi_v_b, phi_a_w, phi_a_b,
                     gamma_v, gamma_a, WM_w, mfold, coef);
  hipLaunchKernelGGL(k2_tables, dim3(49), dim3(256), 0, stream,
                     mfold, WM_b, dw_w, dw_b, pw_w, pw_b, Gt, Ht, baset);
  hipLaunchKernelGGL(k3_main, dim3(BB * (TT / TS)), dim3(256), 0, stream,
                     coef, Gt, Ht, baset, ln_w, ln_b, out);
}